// Round 1
// baseline (195.441 us; speedup 1.0000x reference)
//
#include <hip/hip_runtime.h>
#include <math.h>

#define NBATCH 32
#define S      49152
#define FRAMEN 2048
#define NF     24          // frames
#define NB     16          // biquads
#define CHUNK  64
#define NCH    (S / CHUNK)     // 768 chunks = threads per block
#define NWAVE  (NCH / 64)      // 12 waves

__device__ __forceinline__ float clampf(float x, float lo, float hi) {
    return fminf(fmaxf(x, lo), hi);
}

__global__ __launch_bounds__(NCH)
void biquad_chain_kernel(const float* __restrict__ audio,
                         const float* __restrict__ params,
                         float* __restrict__ out)
{
    // per (filter, frame): a1,a2,a3,m0,m1,m2, M00,M01,M10,M11  (M = T^64)
    __shared__ float sc[NB][NF][10];
    __shared__ float sgain[2][NF];      // [0]=in gain, [1]=out gain
    __shared__ float sagg[NWAVE][6];    // wave aggregates for the scan

    const int t    = threadIdx.x;
    const int b    = blockIdx.x;
    const int lane = t & 63;
    const int wave = t >> 6;

    // ---------------- coefficient init (threads 0..383) ----------------
    if (t < NB * NF) {
        const int f  = t / NF;
        const int fr = t % NF;
        const float* P = params + (size_t)b * 50 * NF;
        const float fn = P[(3 * f + 0) * NF + fr];
        const float gn = P[(3 * f + 1) * NF + fr];
        const float qn = P[(3 * f + 2) * NF + fr];

        float Q = expf(logf(0.5f) + qn * (logf(16.0f) - logf(0.5f)));
        Q = clampf(Q, 0.1f, 100.0f);

        float lo, hi;
        int type;                        // 0 hp, 1 lp, 2 peak, 3 lowshelf, 4 highshelf
        if      (f == 0)  { lo = 20.0f;   hi = 500.0f;   type = 0; }
        else if (f == 15) { lo = 5000.0f; hi = 20000.0f; type = 1; }
        else if (f == 1)  { lo = 50.0f;   hi = 16000.0f; type = 3; }
        else if (f == 14) { lo = 50.0f;   hi = 16000.0f; type = 4; }
        else              { lo = 100.0f;  hi = 15000.0f; type = 2; }

        const float fc = expf(logf(lo) + fn * (logf(hi) - logf(lo)));
        float g = tanf((float)M_PI * fc / 96000.0f);
        g = clampf(g, 1e-6f, 100.0f);
        const float gdb = -24.0f + 48.0f * gn;

        float a1, a2, a3, m0, m1, m2;
        if (type == 0 || type == 1) {
            const float k = 1.0f / Q;
            a1 = 1.0f / (1.0f + g * (g + k)); a2 = g * a1; a3 = g * a2;
            if (type == 0) { m0 = 1.0f; m1 = -k;   m2 = -1.0f; }
            else           { m0 = 0.0f; m1 = 0.0f; m2 = 1.0f;  }
        } else if (type == 2) {
            const float A = powf(10.0f, gdb * (1.0f / 40.0f));
            const float k = (gdb >= 0.0f) ? 1.0f / (Q * A) : A / Q;
            a1 = 1.0f / (1.0f + g * (g + k)); a2 = g * a1; a3 = g * a2;
            m0 = 1.0f; m1 = k * (A * A - 1.0f); m2 = 0.0f;
        } else {
            const float A  = powf(10.0f, gdb * (1.0f / 40.0f));
            const float sA = sqrtf(A);
            const float k  = 1.0f / Q;
            float gs;
            if (type == 3) gs = (gdb >= 0.0f) ? g / sA : g * sA;
            else           gs = (gdb >= 0.0f) ? g * sA : g / sA;
            a1 = 1.0f / (1.0f + gs * (gs + k)); a2 = gs * a1; a3 = gs * a2;
            if (type == 3) { m0 = 1.0f;  m1 = k * (A - 1.0f);      m2 = A * A - 1.0f; }
            else           { m0 = A * A; m1 = k * (1.0f - A) * A;  m2 = 1.0f - A * A; }
        }

        // per-sample state transition matrix T, then M = T^64 by 6 squarings
        float t00 = 2.0f * a1 - 1.0f;
        float t01 = -2.0f * a2;
        float t10 = 2.0f * a1 * a2;
        float t11 = 1.0f - 2.0f * (a2 * a2 + a3);
        #pragma unroll
        for (int i = 0; i < 6; i++) {
            const float n00 = t00 * t00 + t01 * t10;
            const float n01 = t00 * t01 + t01 * t11;
            const float n10 = t10 * t00 + t11 * t10;
            const float n11 = t10 * t01 + t11 * t11;
            t00 = n00; t01 = n01; t10 = n10; t11 = n11;
        }

        sc[f][fr][0] = a1; sc[f][fr][1] = a2; sc[f][fr][2] = a3;
        sc[f][fr][3] = m0; sc[f][fr][4] = m1; sc[f][fr][5] = m2;
        sc[f][fr][6] = t00; sc[f][fr][7] = t01; sc[f][fr][8] = t10; sc[f][fr][9] = t11;
    }
    if (t >= 384 && t < 384 + 2 * NF) {
        const int idx = t - 384;
        const int which = idx / NF;     // 0 = in gain (row 48), 1 = out gain (row 49)
        const int fr    = idx % NF;
        const float* P = params + (size_t)b * 50 * NF;
        const float p  = P[(48 + which) * NF + fr];
        const float db = -60.0f + 60.0f * p;
        sgain[which][fr] = powf(10.0f, db * (1.0f / 20.0f));
    }
    __syncthreads();

    // ---------------- load chunk (with input gain) ----------------
    const int frame = t >> 5;           // 32 chunks per frame
    const float ing = sgain[0][frame];
    float xr[CHUNK];
    {
        const float4* src = (const float4*)(audio + (size_t)b * S + (size_t)t * CHUNK);
        #pragma unroll
        for (int i = 0; i < CHUNK / 4; i++) {
            const float4 v = src[i];
            xr[4 * i + 0] = v.x * ing;
            xr[4 * i + 1] = v.y * ing;
            xr[4 * i + 2] = v.z * ing;
            xr[4 * i + 3] = v.w * ing;
        }
    }

    // ---------------- 16 cascaded stages ----------------
    #pragma unroll 1
    for (int f = 0; f < NB; f++) {
        const float a1  = sc[f][frame][0];
        const float a2  = sc[f][frame][1];
        const float a3  = sc[f][frame][2];
        const float m0  = sc[f][frame][3];
        const float m1  = sc[f][frame][4];
        const float m2  = sc[f][frame][5];
        const float M00 = sc[f][frame][6];
        const float M01 = sc[f][frame][7];
        const float M10 = sc[f][frame][8];
        const float M11 = sc[f][frame][9];

        // Phase A: zero-state run over own chunk -> affine constant c
        float ic1 = 0.0f, ic2 = 0.0f;
        #pragma unroll
        for (int n = 0; n < CHUNK; n++) {
            const float v3 = xr[n] - ic2;
            const float v1 = a1 * ic1 + a2 * v3;
            const float v2 = ic2 + a2 * v1 + a3 * v3;
            ic1 = 2.0f * v1 - ic1;
            ic2 = 2.0f * v2 - ic2;
        }

        // own affine map (A, Ac); wave-level inclusive scan via shfl_up
        float A00 = M00, A01 = M01, A10 = M10, A11 = M11;
        float Ac0 = ic1, Ac1 = ic2;
        #pragma unroll
        for (int d = 1; d < 64; d <<= 1) {
            const float l00 = __shfl_up(A00, d);
            const float l01 = __shfl_up(A01, d);
            const float l10 = __shfl_up(A10, d);
            const float l11 = __shfl_up(A11, d);
            const float lc0 = __shfl_up(Ac0, d);
            const float lc1 = __shfl_up(Ac1, d);
            if (lane >= d) {
                const float n00 = A00 * l00 + A01 * l10;
                const float n01 = A00 * l01 + A01 * l11;
                const float n10 = A10 * l00 + A11 * l10;
                const float n11 = A10 * l01 + A11 * l11;
                const float nc0 = A00 * lc0 + A01 * lc1 + Ac0;
                const float nc1 = A10 * lc0 + A11 * lc1 + Ac1;
                A00 = n00; A01 = n01; A10 = n10; A11 = n11;
                Ac0 = nc0; Ac1 = nc1;
            }
        }

        __syncthreads();   // protect sagg reuse from previous stage
        if (lane == 63) {
            sagg[wave][0] = A00; sagg[wave][1] = A01;
            sagg[wave][2] = A10; sagg[wave][3] = A11;
            sagg[wave][4] = Ac0; sagg[wave][5] = Ac1;
        }
        __syncthreads();

        // wave prefix = compose aggregates of waves 0..wave-1 (in order)
        float W00 = 1.0f, W01 = 0.0f, W10 = 0.0f, W11 = 1.0f, Wc0 = 0.0f, Wc1 = 0.0f;
        for (int k2 = 0; k2 < wave; k2++) {
            const float g00 = sagg[k2][0], g01 = sagg[k2][1];
            const float g10 = sagg[k2][2], g11 = sagg[k2][3];
            const float gc0 = sagg[k2][4], gc1 = sagg[k2][5];
            const float n00 = g00 * W00 + g01 * W10;
            const float n01 = g00 * W01 + g01 * W11;
            const float n10 = g10 * W00 + g11 * W10;
            const float n11 = g10 * W01 + g11 * W11;
            const float nc0 = g00 * Wc0 + g01 * Wc1 + gc0;
            const float nc1 = g10 * Wc0 + g11 * Wc1 + gc1;
            W00 = n00; W01 = n01; W10 = n10; W11 = n11;
            Wc0 = nc0; Wc1 = nc1;
        }

        // incoming state = exclusive prefix applied to zero initial state
        const float P00 = __shfl_up(A00, 1);
        const float P01 = __shfl_up(A01, 1);
        const float P10 = __shfl_up(A10, 1);
        const float P11 = __shfl_up(A11, 1);
        const float Pc0 = __shfl_up(Ac0, 1);
        const float Pc1 = __shfl_up(Ac1, 1);
        float s0, s1;
        if (lane == 0) { s0 = Wc0; s1 = Wc1; }
        else {
            s0 = P00 * Wc0 + P01 * Wc1 + Pc0;
            s1 = P10 * Wc0 + P11 * Wc1 + Pc1;
        }

        // Phase C: true run from incoming state, write outputs in place
        ic1 = s0; ic2 = s1;
        #pragma unroll
        for (int n = 0; n < CHUNK; n++) {
            const float xn = xr[n];
            const float v3 = xn - ic2;
            const float v1 = a1 * ic1 + a2 * v3;
            const float v2 = ic2 + a2 * v1 + a3 * v3;
            xr[n] = m0 * xn + m1 * v1 + m2 * v2;
            ic1 = 2.0f * v1 - ic1;
            ic2 = 2.0f * v2 - ic2;
        }
    }

    // ---------------- store (with output gain) ----------------
    {
        const float og = sgain[1][frame];
        float4* dst = (float4*)(out + (size_t)b * S + (size_t)t * CHUNK);
        #pragma unroll
        for (int i = 0; i < CHUNK / 4; i++) {
            float4 v;
            v.x = xr[4 * i + 0] * og;
            v.y = xr[4 * i + 1] * og;
            v.z = xr[4 * i + 2] * og;
            v.w = xr[4 * i + 3] * og;
            dst[i] = v;
        }
    }
}

extern "C" void kernel_launch(void* const* d_in, const int* in_sizes, int n_in,
                              void* d_out, int out_size, void* d_ws, size_t ws_size,
                              hipStream_t stream)
{
    const float* audio  = (const float*)d_in[0];
    const float* params = (const float*)d_in[1];
    float* out = (float*)d_out;
    biquad_chain_kernel<<<NBATCH, NCH, 0, stream>>>(audio, params, out);
}